// Round 4
// baseline (383.080 us; speedup 1.0000x reference)
//
#include <hip/hip_runtime.h>
#include <stdint.h>

typedef __attribute__((ext_vector_type(4))) float f32x4;
typedef __attribute__((ext_vector_type(8))) __bf16 bf16x8;
typedef unsigned short u16;

#define AS1 __attribute__((address_space(1)))
#define AS3 __attribute__((address_space(3)))

__device__ __forceinline__ u16 f2bf(float f) {
  uint32_t u = __float_as_uint(f);
  u += 0x7fffu + ((u >> 16) & 1u);
  return (u16)(u >> 16);
}
__device__ __forceinline__ float bf2f(u16 s) {
  return __uint_as_float(((uint32_t)s) << 16);
}

__device__ __forceinline__ void gload_lds16(const void* g, void* l) {
  __builtin_amdgcn_global_load_lds((const AS1 void*)g, (AS3 void*)l, 16, 0, 0);
}

// ---------------------------------------------------------------------------
// Kernel 0: f32 -> bf16 convert (RNE). 8 elements/thread, 16B stores.
// ---------------------------------------------------------------------------
__global__ __launch_bounds__(256) void cvt_f32_bf16(const float* __restrict__ src,
                                                    u16* __restrict__ dst) {
  const int i = blockIdx.x * 256 + threadIdx.x;  // 8 elems per thread
  const f32x4 a = ((const f32x4*)src)[2 * i];
  const f32x4 b = ((const f32x4*)src)[2 * i + 1];
  ushort4 lo, hi;
  lo.x = f2bf(a.x); lo.y = f2bf(a.y); lo.z = f2bf(a.z); lo.w = f2bf(a.w);
  hi.x = f2bf(b.x); hi.y = f2bf(b.y); hi.z = f2bf(b.z); hi.w = f2bf(b.w);
  ((ushort4*)dst)[2 * i] = lo;
  ((ushort4*)dst)[2 * i + 1] = hi;
}

// ---------------------------------------------------------------------------
// Kernel 1: qkv = x @ w^T  (M=16384, K=1024, O=3072), bf16 in.
// m97-verified structure: 128x128 tile, BK=64, 4 waves (2x2 of 64x64),
// mfma_f32_16x16x32_bf16, global_load_lds width=16.
// Output routing: o-cols [0,1024) = Q -> d_out as FLOAT32 [b,h,n,d];
// o-cols [1024,3072) = K,V -> ws bf16 as [row][2048] (k | v per row).
// ---------------------------------------------------------------------------
__global__ __launch_bounds__(256) void qkv_gemm(const u16* __restrict__ X,
                                                const u16* __restrict__ W,
                                                float* __restrict__ QOUT,
                                                u16* __restrict__ KV) {
  __shared__ __attribute__((aligned(16))) u16 As[128 * 64];
  __shared__ __attribute__((aligned(16))) u16 Bs[128 * 64];

  const int t = threadIdx.x;
  const int mblk = blockIdx.y << 7;
  const int oblk = blockIdx.x << 7;
  const int wv = t >> 6;
  const int lane = t & 63;
  const int wm = (wv >> 1) << 6;  // 0 or 64
  const int wn = (wv & 1) << 6;   // 0 or 64
  const int lr = lane & 15;       // row/col within 16x16 tile
  const int lq = lane >> 4;       // quad 0..3

  f32x4 acc[4][4];
#pragma unroll
  for (int i = 0; i < 4; i++)
#pragma unroll
    for (int j = 0; j < 4; j++) acc[i][j] = (f32x4){0.f, 0.f, 0.f, 0.f};

  const int srow = t >> 3;  // 0..31
  const int sp = t & 7;     // 16B chunk 0..7

  for (int k0 = 0; k0 < 1024; k0 += 64) {
#pragma unroll
    for (int i = 0; i < 4; i++) {
      const int ml = (i << 5) + srow;  // tile row 0..127
      const u16* ga = X + (size_t)(mblk + ml) * 1024 + k0 + (sp << 3);
      gload_lds16(ga, (char*)As + (i << 12) + (t << 4));
      const u16* gb = W + (size_t)(oblk + ml) * 1024 + k0 + (sp << 3);
      gload_lds16(gb, (char*)Bs + (i << 12) + (t << 4));
    }
    __syncthreads();

#pragma unroll
    for (int kk = 0; kk < 2; kk++) {
      bf16x8 af[4], bfr[4];
#pragma unroll
      for (int i = 0; i < 4; i++) {
        const int ml = wm + (i << 4) + lr;
        af[i] = *(const bf16x8*)((const char*)As + ml * 128 + (((kk << 2) + lq) << 4));
        const int ol = wn + (i << 4) + lr;
        bfr[i] = *(const bf16x8*)((const char*)Bs + ol * 128 + (((kk << 2) + lq) << 4));
      }
#pragma unroll
      for (int i = 0; i < 4; i++)
#pragma unroll
        for (int j = 0; j < 4; j++)
          acc[i][j] = __builtin_amdgcn_mfma_f32_16x16x32_bf16(af[i], bfr[j],
                                                              acc[i][j], 0, 0, 0);
    }
    __syncthreads();
  }

  // epilogue: C/D layout col=lane&15, row=(lane>>4)*4+reg  [m89-verified]
  const bool is_q = (oblk < 1024);
#pragma unroll
  for (int i = 0; i < 4; i++) {
    const int row0 = mblk + wm + (i << 4) + (lq << 2);
#pragma unroll
    for (int j = 0; j < 4; j++) {
      const int col = oblk + wn + (j << 4) + lr;
#pragma unroll
      for (int r = 0; r < 4; r++) {
        const int row = row0 + r;
        if (is_q) {
          const int b = row >> 12, n = row & 4095;
          const int h = col >> 6, d = col & 63;
          QOUT[(((size_t)((b << 4) + h) << 12) + n) * 64 + d] = acc[i][j][r];
        } else {
          KV[(size_t)row * 2048 + (col - 1024)] = f2bf(acc[i][j][r]);
        }
      }
    }
  }
}

// ---------------------------------------------------------------------------
// Kernel 2: ctxraw[bh][d][e] += sum_n exp(k[n,d]) * v[n,e]
//           colsum[bh][d]    += sum_n exp(k[n,d])
// KV layout: [row 16384][2048] = k(1024: h*64+d) | v(1024: h*64+e).
// grid (8 n-chunks of 512, 64 bh). 256 threads = 16x16, each owns 4x4.
// ---------------------------------------------------------------------------
__global__ __launch_bounds__(256) void ctx_colsum(const u16* __restrict__ KV,
                                                  float* __restrict__ ctxraw,
                                                  float* __restrict__ colsum) {
  __shared__ __attribute__((aligned(16))) float ek[16 * 64];
  __shared__ __attribute__((aligned(16))) float ev[16 * 64];

  const int t = threadIdx.x;
  const int bh = blockIdx.y;
  const int b = bh >> 4, h = bh & 15;
  const u16* kb = KV + ((size_t)b << 12) * 2048 + (h << 6);
  const int tr = t >> 4, tc = t & 15;
  const int sn = t >> 6, sc = t & 63;

  float acc[4][4] = {};
  float rs[4] = {0.f, 0.f, 0.f, 0.f};

  const int n0b = blockIdx.x << 9;
  for (int n0 = n0b; n0 < n0b + 512; n0 += 16) {
    __syncthreads();
#pragma unroll
    for (int j = 0; j < 4; j++) {
      const int nl = sn + (j << 2);
      const size_t roff = (size_t)(n0 + nl) * 2048;
      ek[(nl << 6) + sc] = __expf(bf2f(kb[roff + sc]));
      ev[(nl << 6) + sc] = bf2f(kb[roff + 1024 + sc]);
    }
    __syncthreads();
#pragma unroll
    for (int nl = 0; nl < 16; nl++) {
      const f32x4 ka = *(const f32x4*)&ek[(nl << 6) + (tr << 2)];
      const f32x4 vb = *(const f32x4*)&ev[(nl << 6) + (tc << 2)];
      rs[0] += ka.x; rs[1] += ka.y; rs[2] += ka.z; rs[3] += ka.w;
#pragma unroll
      for (int a = 0; a < 4; a++) {
        acc[a][0] += ka[a] * vb.x;
        acc[a][1] += ka[a] * vb.y;
        acc[a][2] += ka[a] * vb.z;
        acc[a][3] += ka[a] * vb.w;
      }
    }
  }

  float* dst = ctxraw + ((size_t)bh << 12);
#pragma unroll
  for (int a = 0; a < 4; a++)
#pragma unroll
    for (int e = 0; e < 4; e++)
      atomicAdd(&dst[((tr << 2) + a) * 64 + (tc << 2) + e], acc[a][e]);
  if (tc == 0) {
#pragma unroll
    for (int a = 0; a < 4; a++) atomicAdd(&colsum[(bh << 6) + (tr << 2) + a], rs[a]);
  }
}

// ---------------------------------------------------------------------------
// Kernel 3: out[bh,n,e] = (0.125/rowsum_n) * sum_d exp(q[n,d]) * ctx'[d,e]
// ctx'[d,e] = ctxraw[d,e]/colsum[d].  Q lives in d_out as FLOAT32 [b,h,n,d];
// each block reads exactly the 64x64 f32 tile it later overwrites (in-place,
// no cross-block aliasing).  qt transposed [d][n] with XOR chunk swizzle
// (chunk ^= d>>2) so writes and b128 reads are both <=2-way (free).
// grid (64 n-chunks of 64, 64 bh).
// ---------------------------------------------------------------------------
__global__ __launch_bounds__(256) void out_kernel(const float* __restrict__ ctxraw,
                                                  const float* __restrict__ colsum,
                                                  float* __restrict__ OUT) {
  __shared__ __attribute__((aligned(16))) float ctxs[64 * 64];  // normalized ctx
  __shared__ __attribute__((aligned(16))) float qt[64 * 64];    // exp(q) [d][n], swizzled

  const int t = threadIdx.x;
  const int bh = blockIdx.y;
  const float* craw = ctxraw + ((size_t)bh << 12);
  const float* csum = colsum + (bh << 6);

#pragma unroll
  for (int j = 0; j < 16; j++) {
    const int idx = (j << 8) + t;
    ctxs[idx] = craw[idx] / csum[idx >> 6];
  }

  const int n0 = blockIdx.x << 6;
  float* qbase = OUT + (((size_t)bh << 12) + n0) * 64;  // 64 n-rows x 64 d, f32
  {
#pragma unroll
    for (int p = 0; p < 4; p++) {
      const int c = (p << 8) + t;      // 0..1023 chunks of 4 floats
      const int nl = c >> 4;           // n-row 0..63
      const int dg = c & 15;           // d-group (4 floats)
      const f32x4 qv = *(const f32x4*)(qbase + nl * 64 + (dg << 2));
      const int swz = ((nl >> 2) ^ dg) << 2;  // chunk swizzle
#pragma unroll
      for (int e = 0; e < 4; e++) {
        const int d = (dg << 2) + e;
        qt[(d << 6) + swz + (nl & 3)] = __expf(qv[e]);
      }
    }
  }
  __syncthreads();

  const int tr = t >> 4, tc = t & 15;
  float acc[4][4] = {};
  f32x4 rsv = {0.f, 0.f, 0.f, 0.f};
#pragma unroll 4
  for (int d = 0; d < 64; d++) {
    const f32x4 qa = *(const f32x4*)&qt[(d << 6) + ((tr ^ (d >> 2)) << 2)];
    const f32x4 cb = *(const f32x4*)&ctxs[(d << 6) + (tc << 2)];
    rsv += qa;
#pragma unroll
    for (int a = 0; a < 4; a++) {
      acc[a][0] += qa[a] * cb.x;
      acc[a][1] += qa[a] * cb.y;
      acc[a][2] += qa[a] * cb.z;
      acc[a][3] += qa[a] * cb.w;
    }
  }
  __syncthreads();  // all reads of the q tile done before in-place overwrite

#pragma unroll
  for (int a = 0; a < 4; a++) {
    const float inv = 0.125f / rsv[a];
    const int row = (tr << 2) + a;
    f32x4 pk;
    pk.x = acc[a][0] * inv;
    pk.y = acc[a][1] * inv;
    pk.z = acc[a][2] * inv;
    pk.w = acc[a][3] * inv;
    *(f32x4*)(qbase + row * 64 + (tc << 2)) = pk;
  }
}

extern "C" void kernel_launch(void* const* d_in, const int* in_sizes, int n_in,
                              void* d_out, int out_size, void* d_ws, size_t ws_size,
                              hipStream_t stream) {
  const float* Xf = (const float*)d_in[0];  // x: [4,4096,1024] float32
  const float* Wf = (const float*)d_in[1];  // w_qkv: [3072,1024] float32

  // ws layout (bytes):
  //   x16: bf16 [16384][1024]                      0      .. 33.55 MB
  //   w16: bf16 [3072][1024]                       +33.55 .. 39.85 MB
  //   KV : bf16 [16384][2048]                      +39.85 .. 106.95 MB
  //   ctxraw fp32 64*64*64, colsum fp32 64*64      +106.95 .. ~108 MB
  u16* x16 = (u16*)d_ws;
  u16* w16 = x16 + (size_t)16384 * 1024;
  u16* KV = w16 + (size_t)3072 * 1024;
  float* ctxraw = (float*)(KV + (size_t)16384 * 2048);
  float* colsum = ctxraw + 64 * 64 * 64;
  float* QOUT = (float*)d_out;  // f32: Q staged [b,h,n,d], overwritten in-place

  hipMemsetAsync(ctxraw, 0, (64 * 64 * 64 + 64 * 64) * sizeof(float), stream);
  cvt_f32_bf16<<<dim3(8192), 256, 0, stream>>>(Xf, x16);   // 16.78M elems
  cvt_f32_bf16<<<dim3(1536), 256, 0, stream>>>(Wf, w16);   // 3.15M elems
  qkv_gemm<<<dim3(24, 128), 256, 0, stream>>>(x16, w16, QOUT, KV);
  ctx_colsum<<<dim3(8, 64), 256, 0, stream>>>(KV, ctxraw, colsum);
  out_kernel<<<dim3(64, 64), 256, 0, stream>>>(ctxraw, colsum, QOUT);
}

// Round 5
// 381.838 us; speedup vs baseline: 1.0033x; 1.0033x over previous
//
#include <hip/hip_runtime.h>
#include <stdint.h>

typedef __attribute__((ext_vector_type(4))) float f32x4;
typedef __attribute__((ext_vector_type(8))) __bf16 bf16x8;
typedef unsigned short u16;

#define AS1 __attribute__((address_space(1)))
#define AS3 __attribute__((address_space(3)))

__device__ __forceinline__ u16 f2bf(float f) {
  uint32_t u = __float_as_uint(f);
  u += 0x7fffu + ((u >> 16) & 1u);
  return (u16)(u >> 16);
}
__device__ __forceinline__ float bf2f(u16 s) {
  return __uint_as_float(((uint32_t)s) << 16);
}

__device__ __forceinline__ void gload_lds16(const void* g, void* l) {
  __builtin_amdgcn_global_load_lds((const AS1 void*)g, (AS3 void*)l, 16, 0, 0);
}

// ---------------------------------------------------------------------------
// Kernel 0: f32 -> bf16 convert (RNE), x and w in one dispatch.
// blocks [0,8192) -> x (16.78M elems), [8192,9728) -> w (3.15M elems).
// ---------------------------------------------------------------------------
__global__ __launch_bounds__(256) void cvt_all(const float* __restrict__ X,
                                               const float* __restrict__ W,
                                               u16* __restrict__ x16,
                                               u16* __restrict__ w16) {
  const int gb = blockIdx.x;
  const float* src;
  u16* dst;
  int i;
  if (gb < 8192) {
    src = X; dst = x16; i = gb * 256 + threadIdx.x;
  } else {
    src = W; dst = w16; i = (gb - 8192) * 256 + threadIdx.x;
  }
  const f32x4 a = ((const f32x4*)src)[2 * i];
  const f32x4 b = ((const f32x4*)src)[2 * i + 1];
  ushort4 lo, hi;
  lo.x = f2bf(a.x); lo.y = f2bf(a.y); lo.z = f2bf(a.z); lo.w = f2bf(a.w);
  hi.x = f2bf(b.x); hi.y = f2bf(b.y); hi.z = f2bf(b.z); hi.w = f2bf(b.w);
  ((ushort4*)dst)[2 * i] = lo;
  ((ushort4*)dst)[2 * i + 1] = hi;
}

// ---------------------------------------------------------------------------
// Kernel 1: qkv = x @ w^T  (M=16384, K=1024, O=3072), bf16 in.  [unchanged]
// m97-verified structure: 128x128 tile, BK=64, 4 waves (2x2 of 64x64),
// mfma_f32_16x16x32_bf16, global_load_lds width=16.
// o-cols [0,1024) = Q -> d_out as f32 [b,h,n,d]; [1024,3072) = K,V -> ws bf16.
// ---------------------------------------------------------------------------
__global__ __launch_bounds__(256) void qkv_gemm(const u16* __restrict__ X,
                                                const u16* __restrict__ W,
                                                float* __restrict__ QOUT,
                                                u16* __restrict__ KV) {
  __shared__ __attribute__((aligned(16))) u16 As[128 * 64];
  __shared__ __attribute__((aligned(16))) u16 Bs[128 * 64];

  const int t = threadIdx.x;
  const int mblk = blockIdx.y << 7;
  const int oblk = blockIdx.x << 7;
  const int wv = t >> 6;
  const int lane = t & 63;
  const int wm = (wv >> 1) << 6;
  const int wn = (wv & 1) << 6;
  const int lr = lane & 15;
  const int lq = lane >> 4;

  f32x4 acc[4][4];
#pragma unroll
  for (int i = 0; i < 4; i++)
#pragma unroll
    for (int j = 0; j < 4; j++) acc[i][j] = (f32x4){0.f, 0.f, 0.f, 0.f};

  const int srow = t >> 3;
  const int sp = t & 7;

  for (int k0 = 0; k0 < 1024; k0 += 64) {
#pragma unroll
    for (int i = 0; i < 4; i++) {
      const int ml = (i << 5) + srow;
      const u16* ga = X + (size_t)(mblk + ml) * 1024 + k0 + (sp << 3);
      gload_lds16(ga, (char*)As + (i << 12) + (t << 4));
      const u16* gb = W + (size_t)(oblk + ml) * 1024 + k0 + (sp << 3);
      gload_lds16(gb, (char*)Bs + (i << 12) + (t << 4));
    }
    __syncthreads();

#pragma unroll
    for (int kk = 0; kk < 2; kk++) {
      bf16x8 af[4], bfr[4];
#pragma unroll
      for (int i = 0; i < 4; i++) {
        const int ml = wm + (i << 4) + lr;
        af[i] = *(const bf16x8*)((const char*)As + ml * 128 + (((kk << 2) + lq) << 4));
        const int ol = wn + (i << 4) + lr;
        bfr[i] = *(const bf16x8*)((const char*)Bs + ol * 128 + (((kk << 2) + lq) << 4));
      }
#pragma unroll
      for (int i = 0; i < 4; i++)
#pragma unroll
        for (int j = 0; j < 4; j++)
          acc[i][j] = __builtin_amdgcn_mfma_f32_16x16x32_bf16(af[i], bfr[j],
                                                              acc[i][j], 0, 0, 0);
    }
    __syncthreads();
  }

  const bool is_q = (oblk < 1024);
#pragma unroll
  for (int i = 0; i < 4; i++) {
    const int row0 = mblk + wm + (i << 4) + (lq << 2);
#pragma unroll
    for (int j = 0; j < 4; j++) {
      const int col = oblk + wn + (j << 4) + lr;
#pragma unroll
      for (int r = 0; r < 4; r++) {
        const int row = row0 + r;
        if (is_q) {
          const int b = row >> 12, n = row & 4095;
          const int h = col >> 6, d = col & 63;
          QOUT[(((size_t)((b << 4) + h) << 12) + n) * 64 + d] = acc[i][j][r];
        } else {
          KV[(size_t)row * 2048 + (col - 1024)] = f2bf(acc[i][j][r]);
        }
      }
    }
  }
}

// ---------------------------------------------------------------------------
// Kernel 2 v2: ctxraw[bh][d][e] += sum_n exp(k[n,d]) * v[n,e]; colsum likewise.
// grid (16 n-chunks of 256, 64 bh) = 1024 blocks (4/CU).  Vector uint2 loads,
// prefetch next 16-row chunk between barrier and compute, XOR-swizzled f32x4
// LDS staging (2-way max = free).  256 threads = 16x16, each owns 4x4.
// ---------------------------------------------------------------------------
__global__ __launch_bounds__(256) void ctx_colsum(const u16* __restrict__ KV,
                                                  float* __restrict__ ctxraw,
                                                  float* __restrict__ colsum) {
  __shared__ __attribute__((aligned(16))) float ek[16 * 64];
  __shared__ __attribute__((aligned(16))) float ev[16 * 64];

  const int t = threadIdx.x;
  const int bh = blockIdx.y;
  const int b = bh >> 4, h = bh & 15;
  const u16* kb = KV + ((size_t)b << 12) * 2048 + (h << 6);
  const int tr = t >> 4, tc = t & 15;
  const int srow = t >> 4;  // row within 16-row chunk
  const int sq = t & 15;    // 4-elem quarter within 64

  float acc[4][4] = {};
  float rs[4] = {0.f, 0.f, 0.f, 0.f};

  const int n0b = blockIdx.x << 8;  // 256 rows per block

  uint2 pk, pv;
  {
    const size_t roff = (size_t)(n0b + srow) * 2048 + (sq << 2);
    pk = *(const uint2*)(kb + roff);
    pv = *(const uint2*)(kb + roff + 1024);
  }

  for (int c = 0; c < 16; c++) {
    {
      f32x4 ke, vv;
      ke.x = __expf(bf2f((u16)(pk.x & 0xffff)));
      ke.y = __expf(bf2f((u16)(pk.x >> 16)));
      ke.z = __expf(bf2f((u16)(pk.y & 0xffff)));
      ke.w = __expf(bf2f((u16)(pk.y >> 16)));
      vv.x = bf2f((u16)(pv.x & 0xffff));
      vv.y = bf2f((u16)(pv.x >> 16));
      vv.z = bf2f((u16)(pv.y & 0xffff));
      vv.w = bf2f((u16)(pv.y >> 16));
      const int p = (sq ^ srow) & 15;
      *(f32x4*)&ek[(srow << 6) + (p << 2)] = ke;
      *(f32x4*)&ev[(srow << 6) + (p << 2)] = vv;
    }
    __syncthreads();
    if (c + 1 < 16) {  // prefetch next chunk; latency hidden by compute below
      const size_t roff = (size_t)(n0b + ((c + 1) << 4) + srow) * 2048 + (sq << 2);
      pk = *(const uint2*)(kb + roff);
      pv = *(const uint2*)(kb + roff + 1024);
    }
#pragma unroll
    for (int nl = 0; nl < 16; nl++) {
      const f32x4 ka = *(const f32x4*)&ek[(nl << 6) + (((tr ^ nl) & 15) << 2)];
      const f32x4 vb = *(const f32x4*)&ev[(nl << 6) + (((tc ^ nl) & 15) << 2)];
      rs[0] += ka.x; rs[1] += ka.y; rs[2] += ka.z; rs[3] += ka.w;
#pragma unroll
      for (int a = 0; a < 4; a++) {
        acc[a][0] += ka[a] * vb.x;
        acc[a][1] += ka[a] * vb.y;
        acc[a][2] += ka[a] * vb.z;
        acc[a][3] += ka[a] * vb.w;
      }
    }
    __syncthreads();
  }

  float* dst = ctxraw + ((size_t)bh << 12);
#pragma unroll
  for (int a = 0; a < 4; a++)
#pragma unroll
    for (int e = 0; e < 4; e++)
      atomicAdd(&dst[((tr << 2) + a) * 64 + (tc << 2) + e], acc[a][e]);
  if (tc == 0) {
#pragma unroll
    for (int a = 0; a < 4; a++) atomicAdd(&colsum[(bh << 6) + (tr << 2) + a], rs[a]);
  }
}

// ---------------------------------------------------------------------------
// Kernel 3: out[bh,n,e] = (0.125/rowsum_n) * sum_d exp(q[n,d]) * ctx'[d,e]
// [unchanged]  Q staged as f32 in d_out [b,h,n,d], overwritten in-place.
// ---------------------------------------------------------------------------
__global__ __launch_bounds__(256) void out_kernel(const float* __restrict__ ctxraw,
                                                  const float* __restrict__ colsum,
                                                  float* __restrict__ OUT) {
  __shared__ __attribute__((aligned(16))) float ctxs[64 * 64];
  __shared__ __attribute__((aligned(16))) float qt[64 * 64];

  const int t = threadIdx.x;
  const int bh = blockIdx.y;
  const float* craw = ctxraw + ((size_t)bh << 12);
  const float* csum = colsum + (bh << 6);

#pragma unroll
  for (int j = 0; j < 16; j++) {
    const int idx = (j << 8) + t;
    ctxs[idx] = craw[idx] / csum[idx >> 6];
  }

  const int n0 = blockIdx.x << 6;
  float* qbase = OUT + (((size_t)bh << 12) + n0) * 64;
  {
#pragma unroll
    for (int p = 0; p < 4; p++) {
      const int c = (p << 8) + t;
      const int nl = c >> 4;
      const int dg = c & 15;
      const f32x4 qv = *(const f32x4*)(qbase + nl * 64 + (dg << 2));
      const int swz = ((nl >> 2) ^ dg) << 2;
#pragma unroll
      for (int e = 0; e < 4; e++) {
        const int d = (dg << 2) + e;
        qt[(d << 6) + swz + (nl & 3)] = __expf(qv[e]);
      }
    }
  }
  __syncthreads();

  const int tr = t >> 4, tc = t & 15;
  float acc[4][4] = {};
  f32x4 rsv = {0.f, 0.f, 0.f, 0.f};
#pragma unroll 4
  for (int d = 0; d < 64; d++) {
    const f32x4 qa = *(const f32x4*)&qt[(d << 6) + ((tr ^ (d >> 2)) << 2)];
    const f32x4 cb = *(const f32x4*)&ctxs[(d << 6) + (tc << 2)];
    rsv += qa;
#pragma unroll
    for (int a = 0; a < 4; a++) {
      acc[a][0] += qa[a] * cb.x;
      acc[a][1] += qa[a] * cb.y;
      acc[a][2] += qa[a] * cb.z;
      acc[a][3] += qa[a] * cb.w;
    }
  }
  __syncthreads();

#pragma unroll
  for (int a = 0; a < 4; a++) {
    const float inv = 0.125f / rsv[a];
    const int row = (tr << 2) + a;
    f32x4 pk;
    pk.x = acc[a][0] * inv;
    pk.y = acc[a][1] * inv;
    pk.z = acc[a][2] * inv;
    pk.w = acc[a][3] * inv;
    *(f32x4*)(qbase + row * 64 + (tc << 2)) = pk;
  }
}

extern "C" void kernel_launch(void* const* d_in, const int* in_sizes, int n_in,
                              void* d_out, int out_size, void* d_ws, size_t ws_size,
                              hipStream_t stream) {
  const float* Xf = (const float*)d_in[0];
  const float* Wf = (const float*)d_in[1];

  u16* x16 = (u16*)d_ws;
  u16* w16 = x16 + (size_t)16384 * 1024;
  u16* KV = w16 + (size_t)3072 * 1024;
  float* ctxraw = (float*)(KV + (size_t)16384 * 2048);
  float* colsum = ctxraw + 64 * 64 * 64;
  float* QOUT = (float*)d_out;

  hipMemsetAsync(ctxraw, 0, (64 * 64 * 64 + 64 * 64) * sizeof(float), stream);
  cvt_all<<<dim3(9728), 256, 0, stream>>>(Xf, Wf, x16, w16);
  qkv_gemm<<<dim3(24, 128), 256, 0, stream>>>(x16, w16, QOUT, KV);
  ctx_colsum<<<dim3(16, 64), 256, 0, stream>>>(KV, ctxraw, colsum);
  out_kernel<<<dim3(64, 64), 256, 0, stream>>>(ctxraw, colsum, QOUT);
}

// Round 6
// 369.515 us; speedup vs baseline: 1.0367x; 1.0334x over previous
//
#include <hip/hip_runtime.h>
#include <stdint.h>

typedef __attribute__((ext_vector_type(4))) float f32x4;
typedef __attribute__((ext_vector_type(16))) float f32x16;
typedef __attribute__((ext_vector_type(8))) __bf16 bf16x8;
typedef unsigned short u16;

#define AS1 __attribute__((address_space(1)))
#define AS3 __attribute__((address_space(3)))

__device__ __forceinline__ u16 f2bf(float f) {
  uint32_t u = __float_as_uint(f);
  u += 0x7fffu + ((u >> 16) & 1u);
  return (u16)(u >> 16);
}
__device__ __forceinline__ float bf2f(u16 s) {
  return __uint_as_float(((uint32_t)s) << 16);
}

__device__ __forceinline__ void gload_lds16(const void* g, void* l) {
  __builtin_amdgcn_global_load_lds((const AS1 void*)g, (AS3 void*)l, 16, 0, 0);
}

// ---------------------------------------------------------------------------
// Kernel 0: f32 -> bf16 convert (x, w) + zero-init of ctxraw/colsum, one dispatch.
// blocks [0,8192) -> x ; [8192,9728) -> w ; [9728,9732) -> zero ctx (66560 f32x4).
// ---------------------------------------------------------------------------
__global__ __launch_bounds__(256) void cvt_all(const float* __restrict__ X,
                                               const float* __restrict__ W,
                                               u16* __restrict__ x16,
                                               u16* __restrict__ w16,
                                               float* __restrict__ ctxbase) {
  const int gb = blockIdx.x;
  if (gb >= 9728) {  // zero ctxraw (64*64*64) + colsum (64*64) = 66560 f32x4
    const int idx = (gb - 9728) * 256 + threadIdx.x;
    for (int i = idx; i < 66560; i += 1024)
      ((f32x4*)ctxbase)[i] = (f32x4){0.f, 0.f, 0.f, 0.f};
    return;
  }
  const float* src;
  u16* dst;
  int i;
  if (gb < 8192) {
    src = X; dst = x16; i = gb * 256 + threadIdx.x;
  } else {
    src = W; dst = w16; i = (gb - 8192) * 256 + threadIdx.x;
  }
  const f32x4 a = ((const f32x4*)src)[2 * i];
  const f32x4 b = ((const f32x4*)src)[2 * i + 1];
  ushort4 lo, hi;
  lo.x = f2bf(a.x); lo.y = f2bf(a.y); lo.z = f2bf(a.z); lo.w = f2bf(a.w);
  hi.x = f2bf(b.x); hi.y = f2bf(b.y); hi.z = f2bf(b.z); hi.w = f2bf(b.w);
  ((ushort4*)dst)[2 * i] = lo;
  ((ushort4*)dst)[2 * i + 1] = hi;
}

// ---------------------------------------------------------------------------
// Kernel 1 v2: qkv = x @ w^T  (M=16384, K=1024, O=3072), bf16 in.
// 128x128 tile, BK=64, 4 waves (2x2 of 64x64), mfma_f32_32x32x16_bf16
// (4061 FLOP/cyc vs 3378 for 16x16 — m119), half the frag ds_reads.
// XOR chunk swizzle (chunk ^= row&7) folded into the GLOBAL fetch address so
// global_load_lds (LDS addr = base+lane*16) stores LDS[row][p]=G[row][p^(row&7)];
// frag reads then hit all 32 banks at 2-way (free, m136).
// XCD-aware remap: each XCD gets a contiguous mblk stripe x all oblks -> X rows
// reused in-XCD L2.  o-cols [0,1024)=Q -> d_out f32 [b,h,n,d]; rest -> KV bf16.
// ---------------------------------------------------------------------------
__global__ __launch_bounds__(256) void qkv_gemm(const u16* __restrict__ X,
                                                const u16* __restrict__ W,
                                                float* __restrict__ QOUT,
                                                u16* __restrict__ KV) {
  __shared__ __attribute__((aligned(16))) u16 As[128 * 64];
  __shared__ __attribute__((aligned(16))) u16 Bs[128 * 64];

  const int t = threadIdx.x;
  // XCD-aware block remap (perf heuristic only; any mapping is correct)
  const int D = blockIdx.y * 24 + blockIdx.x;  // 0..3071
  const int xcd = D & 7;
  const int s = D >> 3;              // 0..383
  const int oblk = (s % 24) << 7;    // 24 o-blocks
  const int mblk = (((s / 24) << 3) | xcd) << 7;  // 128 m-blocks, striped per XCD

  const int wv = t >> 6;
  const int lane = t & 63;
  const int wm = (wv >> 1) << 6;  // 0 or 64
  const int wn = (wv & 1) << 6;   // 0 or 64
  const int lm = lane & 31;       // row/col within 32x32 tile
  const int lk = lane >> 5;       // k-half (k = lk*8 + j)

  f32x16 acc[2][2];
#pragma unroll
  for (int i = 0; i < 2; i++)
#pragma unroll
    for (int j = 0; j < 2; j++)
#pragma unroll
      for (int r = 0; r < 16; r++) acc[i][j][r] = 0.f;

  const int srow = t >> 3;  // 0..31
  const int sp = t & 7;     // LDS 16B-chunk slot this thread fills

  for (int k0 = 0; k0 < 1024; k0 += 64) {
#pragma unroll
    for (int i = 0; i < 4; i++) {
      const int ml = (i << 5) + srow;  // tile row 0..127
      const int cg = sp ^ (ml & 7);    // global chunk to fetch (swizzle)
      const u16* ga = X + (size_t)(mblk + ml) * 1024 + k0 + (cg << 3);
      gload_lds16(ga, (char*)As + (i << 12) + (t << 4));
      const u16* gb = W + (size_t)(oblk + ml) * 1024 + k0 + (cg << 3);
      gload_lds16(gb, (char*)Bs + (i << 12) + (t << 4));
    }
    __syncthreads();

#pragma unroll
    for (int ks = 0; ks < 4; ks++) {  // 4 k-steps of 16
      bf16x8 af[2], bfr[2];
#pragma unroll
      for (int i = 0; i < 2; i++) {
        const int row = wm + (i << 5) + lm;
        const int pa = ((ks << 1) + lk) ^ (row & 7);
        af[i] = *(const bf16x8*)((const char*)As + row * 128 + (pa << 4));
        const int col = wn + (i << 5) + lm;
        const int pb = ((ks << 1) + lk) ^ (col & 7);
        bfr[i] = *(const bf16x8*)((const char*)Bs + col * 128 + (pb << 4));
      }
#pragma unroll
      for (int i = 0; i < 2; i++)
#pragma unroll
        for (int j = 0; j < 2; j++)
          acc[i][j] = __builtin_amdgcn_mfma_f32_32x32x16_bf16(af[i], bfr[j],
                                                              acc[i][j], 0, 0, 0);
    }
    __syncthreads();
  }

  // epilogue: 32x32 C/D layout col=lane&31, row=(r&3)+8*(r>>2)+4*(lane>>5)
  // [m74/m101-verified]
  const bool is_q = (oblk < 1024);
#pragma unroll
  for (int i = 0; i < 2; i++) {
#pragma unroll
    for (int j = 0; j < 2; j++) {
      const int colg = oblk + wn + (j << 5) + lm;
#pragma unroll
      for (int r = 0; r < 16; r++) {
        const int rowg = mblk + wm + (i << 5) + (r & 3) + ((r >> 2) << 3) + (lk << 2);
        if (is_q) {
          const int b = rowg >> 12, n = rowg & 4095;
          const int h = colg >> 6, d = colg & 63;
          QOUT[(((size_t)((b << 4) + h) << 12) + n) * 64 + d] = acc[i][j][r];
        } else {
          KV[(size_t)rowg * 2048 + (colg - 1024)] = f2bf(acc[i][j][r]);
        }
      }
    }
  }
}

// ---------------------------------------------------------------------------
// Kernel 2: ctxraw[bh][d][e] += sum_n exp(k[n,d]) * v[n,e]; colsum likewise.
// [unchanged from round 5]
// ---------------------------------------------------------------------------
__global__ __launch_bounds__(256) void ctx_colsum(const u16* __restrict__ KV,
                                                  float* __restrict__ ctxraw,
                                                  float* __restrict__ colsum) {
  __shared__ __attribute__((aligned(16))) float ek[16 * 64];
  __shared__ __attribute__((aligned(16))) float ev[16 * 64];

  const int t = threadIdx.x;
  const int bh = blockIdx.y;
  const int b = bh >> 4, h = bh & 15;
  const u16* kb = KV + ((size_t)b << 12) * 2048 + (h << 6);
  const int tr = t >> 4, tc = t & 15;
  const int srow = t >> 4;
  const int sq = t & 15;

  float acc[4][4] = {};
  float rs[4] = {0.f, 0.f, 0.f, 0.f};

  const int n0b = blockIdx.x << 8;

  uint2 pk, pv;
  {
    const size_t roff = (size_t)(n0b + srow) * 2048 + (sq << 2);
    pk = *(const uint2*)(kb + roff);
    pv = *(const uint2*)(kb + roff + 1024);
  }

  for (int c = 0; c < 16; c++) {
    {
      f32x4 ke, vv;
      ke.x = __expf(bf2f((u16)(pk.x & 0xffff)));
      ke.y = __expf(bf2f((u16)(pk.x >> 16)));
      ke.z = __expf(bf2f((u16)(pk.y & 0xffff)));
      ke.w = __expf(bf2f((u16)(pk.y >> 16)));
      vv.x = bf2f((u16)(pv.x & 0xffff));
      vv.y = bf2f((u16)(pv.x >> 16));
      vv.z = bf2f((u16)(pv.y & 0xffff));
      vv.w = bf2f((u16)(pv.y >> 16));
      const int p = (sq ^ srow) & 15;
      *(f32x4*)&ek[(srow << 6) + (p << 2)] = ke;
      *(f32x4*)&ev[(srow << 6) + (p << 2)] = vv;
    }
    __syncthreads();
    if (c + 1 < 16) {
      const size_t roff = (size_t)(n0b + ((c + 1) << 4) + srow) * 2048 + (sq << 2);
      pk = *(const uint2*)(kb + roff);
      pv = *(const uint2*)(kb + roff + 1024);
    }
#pragma unroll
    for (int nl = 0; nl < 16; nl++) {
      const f32x4 ka = *(const f32x4*)&ek[(nl << 6) + (((tr ^ nl) & 15) << 2)];
      const f32x4 vb = *(const f32x4*)&ev[(nl << 6) + (((tc ^ nl) & 15) << 2)];
      rs[0] += ka.x; rs[1] += ka.y; rs[2] += ka.z; rs[3] += ka.w;
#pragma unroll
      for (int a = 0; a < 4; a++) {
        acc[a][0] += ka[a] * vb.x;
        acc[a][1] += ka[a] * vb.y;
        acc[a][2] += ka[a] * vb.z;
        acc[a][3] += ka[a] * vb.w;
      }
    }
    __syncthreads();
  }

  float* dst = ctxraw + ((size_t)bh << 12);
#pragma unroll
  for (int a = 0; a < 4; a++)
#pragma unroll
    for (int e = 0; e < 4; e++)
      atomicAdd(&dst[((tr << 2) + a) * 64 + (tc << 2) + e], acc[a][e]);
  if (tc == 0) {
#pragma unroll
    for (int a = 0; a < 4; a++) atomicAdd(&colsum[(bh << 6) + (tr << 2) + a], rs[a]);
  }
}

// ---------------------------------------------------------------------------
// Kernel 3: out[bh,n,e] = (0.125/rowsum_n) * sum_d exp(q[n,d]) * ctx'[d,e]
// [unchanged]  Q staged as f32 in d_out [b,h,n,d], overwritten in-place.
// ---------------------------------------------------------------------------
__global__ __launch_bounds__(256) void out_kernel(const float* __restrict__ ctxraw,
                                                  const float* __restrict__ colsum,
                                                  float* __restrict__ OUT) {
  __shared__ __attribute__((aligned(16))) float ctxs[64 * 64];
  __shared__ __attribute__((aligned(16))) float qt[64 * 64];

  const int t = threadIdx.x;
  const int bh = blockIdx.y;
  const float* craw = ctxraw + ((size_t)bh << 12);
  const float* csum = colsum + (bh << 6);

#pragma unroll
  for (int j = 0; j < 16; j++) {
    const int idx = (j << 8) + t;
    ctxs[idx] = craw[idx] / csum[idx >> 6];
  }

  const int n0 = blockIdx.x << 6;
  float* qbase = OUT + (((size_t)bh << 12) + n0) * 64;
  {
#pragma unroll
    for (int p = 0; p < 4; p++) {
      const int c = (p << 8) + t;
      const int nl = c >> 4;
      const int dg = c & 15;
      const f32x4 qv = *(const f32x4*)(qbase + nl * 64 + (dg << 2));
      const int swz = ((nl >> 2) ^ dg) << 2;
#pragma unroll
      for (int e = 0; e < 4; e++) {
        const int d = (dg << 2) + e;
        qt[(d << 6) + swz + (nl & 3)] = __expf(qv[e]);
      }
    }
  }
  __syncthreads();

  const int tr = t >> 4, tc = t & 15;
  float acc[4][4] = {};
  f32x4 rsv = {0.f, 0.f, 0.f, 0.f};
#pragma unroll 4
  for (int d = 0; d < 64; d++) {
    const f32x4 qa = *(const f32x4*)&qt[(d << 6) + ((tr ^ (d >> 2)) << 2)];
    const f32x4 cb = *(const f32x4*)&ctxs[(d << 6) + (tc << 2)];
    rsv += qa;
#pragma unroll
    for (int a = 0; a < 4; a++) {
      acc[a][0] += qa[a] * cb.x;
      acc[a][1] += qa[a] * cb.y;
      acc[a][2] += qa[a] * cb.z;
      acc[a][3] += qa[a] * cb.w;
    }
  }
  __syncthreads();

#pragma unroll
  for (int a = 0; a < 4; a++) {
    const float inv = 0.125f / rsv[a];
    const int row = (tr << 2) + a;
    f32x4 pk;
    pk.x = acc[a][0] * inv;
    pk.y = acc[a][1] * inv;
    pk.z = acc[a][2] * inv;
    pk.w = acc[a][3] * inv;
    *(f32x4*)(qbase + row * 64 + (tc << 2)) = pk;
  }
}

extern "C" void kernel_launch(void* const* d_in, const int* in_sizes, int n_in,
                              void* d_out, int out_size, void* d_ws, size_t ws_size,
                              hipStream_t stream) {
  const float* Xf = (const float*)d_in[0];
  const float* Wf = (const float*)d_in[1];

  u16* x16 = (u16*)d_ws;
  u16* w16 = x16 + (size_t)16384 * 1024;
  u16* KV = w16 + (size_t)3072 * 1024;
  float* ctxraw = (float*)(KV + (size_t)16384 * 2048);
  float* colsum = ctxraw + 64 * 64 * 64;
  float* QOUT = (float*)d_out;

  cvt_all<<<dim3(9732), 256, 0, stream>>>(Xf, Wf, x16, w16, ctxraw);
  qkv_gemm<<<dim3(24, 128), 256, 0, stream>>>(x16, w16, QOUT, KV);
  ctx_colsum<<<dim3(16, 64), 256, 0, stream>>>(KV, ctxraw, colsum);
  out_kernel<<<dim3(64, 64), 256, 0, stream>>>(ctxraw, colsum, QOUT);
}